// Round 21
// baseline (78.142 us; speedup 1.0000x reference)
//
#include <hip/hip_runtime.h>
#include <stdint.h>

static constexpr int   Bn      = 32;
static constexpr int   Tn      = 2000;
static constexpr int   Hn      = 512;
static constexpr int   Ln      = 256;     // max_label_len
static constexpr float kThresh = 0.95f;
static constexpr int   TCHUNK  = 80;      // meta granularity (consumer chunk)
static constexpr int   NTCH    = Tn / TCHUNK;   // 25
static constexpr int   MSTRIDE = 32;            // meta entries per row (padded)
static constexpr unsigned PUBF = 0x40000000u;   // published flag (low word)

// ---------------------------------------------------------------------------
// Fused producer-consumer CIF, spill-proof producer.
// R20 (VGPR=44) still spilled part of its 40-float double-buffer; scratch is
// VMEM, so every chunk put a ~300-cyc vmcnt wait INSIDE the serial chain
// (this also retro-explains R10's 46 cyc/step: one ~900-cyc HBM miss per
// 40-step chunk = +22 cyc/step). Fix: producer holds only FOUR NAMED float4
// (16 VGPRs) in a rotation pipeline fed by ds_read_b128 from the LDS-staged
// alpha row. Each q is reloaded immediately after consumption -> 12 steps
// (~144 cyc) of cover >= ~120-cyc LDS latency, all under lgkmcnt. Nothing
// register-hungry remains: NO allocator budget can push this to scratch.
//
// Body = 16 steps x 125 iterations; meta published at iteration starts
// every 5 iterations -> TCHUNK=80 (25 chunks, 800 consumers). Consumers
// (array-free, uniform scalar alpha loads, exclusive segment ownership,
// ascending-t accumulation -- proven absmax 0.0 in R18-R20) each own the
// segments CLOSING in their 80-step chunk; walk-back re-derives the
// straddler opening; tc=24 zero-fills [fc,256). No atomics, no pre-zero.
// ---------------------------------------------------------------------------
__global__ __launch_bounds__(64, 1) void cif_fused_kernel(
    const float* __restrict__ hidden,
    const float* __restrict__ alphas,
    uint64_t* __restrict__ meta,     // [Bn*MSTRIDE]
    float* __restrict__ out) {
  const int lane = threadIdx.x;
  __shared__ __align__(16) float alds[Tn + 64];   // +pad: tail prefetch safe

  if (blockIdx.x < Bn) {
    // ---------------- producer: serial scan for row b ----------------
    __builtin_amdgcn_s_setprio(3);
    const int b = blockIdx.x;
    {  // stage row -> LDS, coalesced (one-time cost, outside the chain)
      const float4* __restrict__ arow =
          reinterpret_cast<const float4*>(alphas + (size_t)b * Tn);
      for (int i = lane; i < Tn / 4; i += 64)
        *reinterpret_cast<float4*>(&alds[4 * i]) = arow[i];
      for (int i = Tn / 4 + lane; i < (Tn + 64) / 4; i += 64)
        *reinterpret_cast<float4*>(&alds[4 * i]) =
            make_float4(0.f, 0.f, 0.f, 0.f);
    }
    __syncthreads();

    const float4* __restrict__ lds4 =
        reinterpret_cast<const float4*>(&alds[0]);
    float I  = 0.0f;
    int   fc = 0;

    float4 q0 = lds4[0], q1 = lds4[1], q2 = lds4[2], q3 = lds4[3];
    int rd = 4;

    auto step4 = [&](const float4& q) {
#pragma unroll
      for (int j = 0; j < 4; ++j) {
        const float a = (j == 0) ? q.x : (j == 1) ? q.y : (j == 2) ? q.z : q.w;
        const float integ = I + a;            // reference op order
        const bool  fire  = integ > kThresh;
        I  = fire ? (integ - 1.0f) : integ;
        fc += fire ? 1 : 0;
      }
    };

    for (int c = 0; c < 125; ++c) {           // 16 steps per iteration
      if (lane == 0 && (c % 5) == 0) {        // state at t = 16c = 80*(c/5)
        const uint64_t v = ((uint64_t)__float_as_uint(I) << 32) |
                           (uint64_t)(PUBF | (unsigned)fc);
        __hip_atomic_store(&meta[(size_t)b * MSTRIDE + c / 5], v,
                           __ATOMIC_RELAXED, __HIP_MEMORY_SCOPE_AGENT);
      }
      step4(q0); q0 = lds4[rd + 0];           // reload right after consume:
      step4(q1); q1 = lds4[rd + 1];           // 12 steps (~144cy) of cover
      step4(q2); q2 = lds4[rd + 2];
      step4(q3); q3 = lds4[rd + 3];
      rd += 4;
    }
    return;
  }

  // ---------------- consumer: (chunk tc, row b), array-free ----------------
  const int idx = blockIdx.x - Bn;
  const int b   = idx & (Bn - 1);
  const int tc  = idx >> 5;                 // low blockIdx -> low tc
  const int t_start = tc * TCHUNK;
  const int col = lane * 8;                 // 8 floats/thread over H=512

  auto wait_meta = [&](int c) -> uint64_t {
    const uint64_t* p = &meta[(size_t)b * MSTRIDE + c];
    uint64_t v;
    for (;;) {
      v = __hip_atomic_load(p, __ATOMIC_RELAXED, __HIP_MEMORY_SCOPE_AGENT);
      if ((unsigned)v & PUBF) break;
      __builtin_amdgcn_s_sleep(16);
    }
    return v;
  };

  const float* __restrict__ arow = alphas + (size_t)b * Tn;

  // Chunk-start state (bit-exact from producer).
  float I; int s;
  if (tc == 0) { I = 0.0f; s = 0; }
  else {
    const uint64_t v = wait_meta(tc);
    I = __uint_as_float((unsigned)(v >> 32));
    s = (int)((unsigned)v & 0xFFFFu);
  }

  // Walk back: find t_prev (last fire before t_start) and its remainder.
  int   t_prev   = -1;
  float rem_prev = 0.0f;
  for (int k = 1; tc - k >= 0 && t_prev < 0; ++k) {
    const int ck = tc - k;
    float Ik;
    if (ck == 0) Ik = 0.0f;
    else {
      const uint64_t v = wait_meta(ck);
      Ik = __uint_as_float((unsigned)(v >> 32));
    }
    const float* __restrict__ ap = arow + ck * TCHUNK;
    int lt = -1; float lrem = 0.0f;
    for (int j = 0; j < TCHUNK; ++j) {
      const float a     = ap[j];               // uniform scalar load
      const float integ = Ik + a;              // reference op order
      const bool  fire  = integ > kThresh;
      if (fire) { lt = ck * TCHUNK + j; lrem = a - (1.0f - Ik); }
      Ik = fire ? (integ - 1.0f) : integ;
    }
    if (lt >= 0) { t_prev = lt; rem_prev = lrem; }
  }

  const float* __restrict__ hb = hidden + (size_t)b * Tn * Hn + col;
  float4 acc0 = make_float4(0.f, 0.f, 0.f, 0.f);
  float4 acc1 = make_float4(0.f, 0.f, 0.f, 0.f);
  float4 h0, h1;

  auto loadh = [&](int t) {
    h0 = *reinterpret_cast<const float4*>(hb + (size_t)t * Hn);
    h1 = *reinterpret_cast<const float4*>(hb + (size_t)t * Hn + 4);
  };
  auto acc8 = [&](float wt) {
    acc0.x += wt * h0.x; acc0.y += wt * h0.y;
    acc0.z += wt * h0.z; acc0.w += wt * h0.w;
    acc1.x += wt * h1.x; acc1.y += wt * h1.y;
    acc1.z += wt * h1.z; acc1.w += wt * h1.w;
  };
  auto set8 = [&](float wt) {
    acc0.x = wt * h0.x; acc0.y = wt * h0.y;
    acc0.z = wt * h0.z; acc0.w = wt * h0.w;
    acc1.x = wt * h1.x; acc1.y = wt * h1.y;
    acc1.z = wt * h1.z; acc1.w = wt * h1.w;
  };

  if (t_prev >= 0) {            // opening: frame = rem * h[t_prev]
    loadh(t_prev);
    set8(rem_prev);
  }
  for (int t = t_prev + 1; t < t_start; ++t) {   // straddler interior rows
    loadh(t);
    acc8(arow[t]);
  }

  // Replay chunk tc; close (and exclusively store) each segment that fires.
  for (int j = 0; j < TCHUNK; ++j) {
    const int   t     = t_start + j;
    const float a     = arow[t];             // uniform scalar load
    const float integ = I + a;               // reference op order
    const bool  fire  = integ > kThresh;     // wave-uniform
    loadh(t);
    if (fire) {
      const float cw = 1.0f - I;             // dist_completion
      acc8(cw);
      if (s < Ln) {
        float* op = out + ((size_t)b * Ln + s) * Hn + col;
        *reinterpret_cast<float4*>(op)     = acc0;
        *reinterpret_cast<float4*>(op + 4) = acc1;
      }
      const float rem = a - cw;              // remainds -> opens next segment
      set8(rem);
      s += 1;
      I  = integ - 1.0f;
    } else {
      acc8(a);
      I = integ;
    }
  }
  // Open tail is owned by consumer (tc+1); nothing more to store...
  if (tc == NTCH - 1) {                      // ...except zero-fill at the end
    const float4 z = make_float4(0.f, 0.f, 0.f, 0.f);
    for (int s2 = s; s2 < Ln; ++s2) {
      float* op = out + ((size_t)b * Ln + s2) * Hn + col;
      *reinterpret_cast<float4*>(op)     = z;
      *reinterpret_cast<float4*>(op + 4) = z;
    }
  }
}

extern "C" void kernel_launch(void* const* d_in, const int* in_sizes, int n_in,
                              void* d_out, int out_size, void* d_ws, size_t ws_size,
                              hipStream_t stream) {
  const float* hidden = (const float*)d_in[0];
  const float* alphas = (const float*)d_in[1];
  float* out = (float*)d_out;

  // ws layout: meta[Bn*MSTRIDE] u64 (8 KB, memset each call -- poison 0xAA
  // would read as published since bit30 of 0xAAAAAAAA is set).
  uint64_t* meta = (uint64_t*)d_ws;
  hipMemsetAsync(meta, 0, (size_t)Bn * MSTRIDE * sizeof(uint64_t), stream);

  const int nblocks = Bn + NTCH * Bn;   // 32 producers + 800 consumers
  cif_fused_kernel<<<nblocks, 64, 0, stream>>>(hidden, alphas, meta, out);
}

// Round 22
// 64.993 us; speedup vs baseline: 1.2023x; 1.2023x over previous
//
#include <hip/hip_runtime.h>
#include <stdint.h>

static constexpr int   Bn      = 32;
static constexpr int   Tn      = 2000;
static constexpr int   Hn      = 512;
static constexpr int   Ln      = 256;     // max_label_len
static constexpr float kThresh = 0.95f;
static constexpr int   TCHUNK  = 40;      // meta granularity (consumer chunk)
static constexpr int   NTCH    = Tn / TCHUNK;   // 50
static constexpr int   MSTRIDE = 64;            // meta entries per row (padded)
static constexpr unsigned PUBF = 0x40000000u;   // published flag (low word)

// ---------------------------------------------------------------------------
// Fused producer-consumer CIF. R22 = R20's consumer geometry (TCHUNK=40,
// 1600 consumers -- occupancy 14% vs R21's 7%, which caused the regression)
// + R21's spill-proof rotation producer adapted to 40-step meta boundaries:
// depth-5 rotation of NAMED float4 (20 VGPRs), iteration = 20 steps, each q
// reloaded via ds_read_b128 right after consumption (16 steps ~190 cyc of
// cover >= ~120 cyc LDS latency, all under lgkmcnt -- NO vmem, NO arrays in
// the serial chain). Meta published on even iterations (t = 20c).
//
// Consumers: R20 verbatim (array-free, uniform scalar alpha loads, exclusive
// ownership of segments closing in the chunk, walk-back for the straddler
// opening, ascending-t accumulation -- absmax 0.0 in R18-R21), tc=NTCH-1
// zero-fills [fc,256). No atomics, no pre-zero pass.
// ---------------------------------------------------------------------------
__global__ __launch_bounds__(64, 1) void cif_fused_kernel(
    const float* __restrict__ hidden,
    const float* __restrict__ alphas,
    uint64_t* __restrict__ meta,     // [Bn*MSTRIDE]
    float* __restrict__ out) {
  const int lane = threadIdx.x;
  __shared__ __align__(16) float alds[Tn + 64];   // +pad: tail prefetch safe

  if (blockIdx.x < Bn) {
    // ---------------- producer: serial scan for row b ----------------
    __builtin_amdgcn_s_setprio(3);
    const int b = blockIdx.x;
    {  // stage row -> LDS, coalesced (one-time cost, outside the chain)
      const float4* __restrict__ arow =
          reinterpret_cast<const float4*>(alphas + (size_t)b * Tn);
      for (int i = lane; i < Tn / 4; i += 64)
        *reinterpret_cast<float4*>(&alds[4 * i]) = arow[i];
      for (int i = Tn / 4 + lane; i < (Tn + 64) / 4; i += 64)
        *reinterpret_cast<float4*>(&alds[4 * i]) =
            make_float4(0.f, 0.f, 0.f, 0.f);
    }
    __syncthreads();

    const float4* __restrict__ lds4 =
        reinterpret_cast<const float4*>(&alds[0]);
    float I  = 0.0f;
    int   fc = 0;

    float4 q0 = lds4[0], q1 = lds4[1], q2 = lds4[2], q3 = lds4[3],
           q4 = lds4[4];
    int rd = 5;

    auto step4 = [&](const float4& q) {
#pragma unroll
      for (int j = 0; j < 4; ++j) {
        const float a = (j == 0) ? q.x : (j == 1) ? q.y : (j == 2) ? q.z : q.w;
        const float integ = I + a;            // reference op order
        const bool  fire  = integ > kThresh;
        I  = fire ? (integ - 1.0f) : integ;
        fc += fire ? 1 : 0;
      }
    };

    for (int c = 0; c < 100; ++c) {           // 20 steps per iteration
      if (lane == 0 && (c & 1) == 0) {        // state at t = 20c -> chunk c/2
        const uint64_t v = ((uint64_t)__float_as_uint(I) << 32) |
                           (uint64_t)(PUBF | (unsigned)fc);
        __hip_atomic_store(&meta[(size_t)b * MSTRIDE + (c >> 1)], v,
                           __ATOMIC_RELAXED, __HIP_MEMORY_SCOPE_AGENT);
      }
      step4(q0); q0 = lds4[rd + 0];           // reload right after consume:
      step4(q1); q1 = lds4[rd + 1];           // 16 steps (~190cy) of cover
      step4(q2); q2 = lds4[rd + 2];
      step4(q3); q3 = lds4[rd + 3];
      step4(q4); q4 = lds4[rd + 4];
      rd += 5;
    }
    return;
  }

  // ---------------- consumer: (chunk tc, row b), array-free ----------------
  const int idx = blockIdx.x - Bn;
  const int b   = idx & (Bn - 1);
  const int tc  = idx >> 5;                 // low blockIdx -> low tc
  const int t_start = tc * TCHUNK;
  const int col = lane * 8;                 // 8 floats/thread over H=512

  auto wait_meta = [&](int c) -> uint64_t {
    const uint64_t* p = &meta[(size_t)b * MSTRIDE + c];
    uint64_t v;
    for (;;) {
      v = __hip_atomic_load(p, __ATOMIC_RELAXED, __HIP_MEMORY_SCOPE_AGENT);
      if ((unsigned)v & PUBF) break;
      __builtin_amdgcn_s_sleep(16);
    }
    return v;
  };

  const float* __restrict__ arow = alphas + (size_t)b * Tn;

  // Chunk-start state (bit-exact from producer).
  float I; int s;
  if (tc == 0) { I = 0.0f; s = 0; }
  else {
    const uint64_t v = wait_meta(tc);
    I = __uint_as_float((unsigned)(v >> 32));
    s = (int)((unsigned)v & 0xFFFFu);
  }

  // Walk back: find t_prev (last fire before t_start) and its remainder.
  int   t_prev   = -1;
  float rem_prev = 0.0f;
  for (int k = 1; tc - k >= 0 && t_prev < 0; ++k) {
    const int ck = tc - k;
    float Ik;
    if (ck == 0) Ik = 0.0f;
    else {
      const uint64_t v = wait_meta(ck);
      Ik = __uint_as_float((unsigned)(v >> 32));
    }
    const float* __restrict__ ap = arow + ck * TCHUNK;
    int lt = -1; float lrem = 0.0f;
#pragma unroll
    for (int j = 0; j < TCHUNK; ++j) {
      const float a     = ap[j];               // uniform scalar load
      const float integ = Ik + a;              // reference op order
      const bool  fire  = integ > kThresh;
      if (fire) { lt = ck * TCHUNK + j; lrem = a - (1.0f - Ik); }
      Ik = fire ? (integ - 1.0f) : integ;
    }
    if (lt >= 0) { t_prev = lt; rem_prev = lrem; }
  }

  const float* __restrict__ hb = hidden + (size_t)b * Tn * Hn + col;
  float4 acc0 = make_float4(0.f, 0.f, 0.f, 0.f);
  float4 acc1 = make_float4(0.f, 0.f, 0.f, 0.f);
  float4 h0, h1;

  auto loadh = [&](int t) {
    h0 = *reinterpret_cast<const float4*>(hb + (size_t)t * Hn);
    h1 = *reinterpret_cast<const float4*>(hb + (size_t)t * Hn + 4);
  };
  auto acc8 = [&](float wt) {
    acc0.x += wt * h0.x; acc0.y += wt * h0.y;
    acc0.z += wt * h0.z; acc0.w += wt * h0.w;
    acc1.x += wt * h1.x; acc1.y += wt * h1.y;
    acc1.z += wt * h1.z; acc1.w += wt * h1.w;
  };
  auto set8 = [&](float wt) {
    acc0.x = wt * h0.x; acc0.y = wt * h0.y;
    acc0.z = wt * h0.z; acc0.w = wt * h0.w;
    acc1.x = wt * h1.x; acc1.y = wt * h1.y;
    acc1.z = wt * h1.z; acc1.w = wt * h1.w;
  };

  if (t_prev >= 0) {            // opening: frame = rem * h[t_prev]
    loadh(t_prev);
    set8(rem_prev);
  }
  for (int t = t_prev + 1; t < t_start; ++t) {   // straddler interior rows
    loadh(t);
    acc8(arow[t]);
  }

  // Replay chunk tc; close (and exclusively store) each segment that fires.
  for (int j = 0; j < TCHUNK; ++j) {
    const int   t     = t_start + j;
    const float a     = arow[t];             // uniform scalar load
    const float integ = I + a;               // reference op order
    const bool  fire  = integ > kThresh;     // wave-uniform
    loadh(t);
    if (fire) {
      const float cw = 1.0f - I;             // dist_completion
      acc8(cw);
      if (s < Ln) {
        float* op = out + ((size_t)b * Ln + s) * Hn + col;
        *reinterpret_cast<float4*>(op)     = acc0;
        *reinterpret_cast<float4*>(op + 4) = acc1;
      }
      const float rem = a - cw;              // remainds -> opens next segment
      set8(rem);
      s += 1;
      I  = integ - 1.0f;
    } else {
      acc8(a);
      I = integ;
    }
  }
  // Open tail is owned by consumer (tc+1); nothing more to store...
  if (tc == NTCH - 1) {                      // ...except zero-fill at the end
    const float4 z = make_float4(0.f, 0.f, 0.f, 0.f);
    for (int s2 = s; s2 < Ln; ++s2) {
      float* op = out + ((size_t)b * Ln + s2) * Hn + col;
      *reinterpret_cast<float4*>(op)     = z;
      *reinterpret_cast<float4*>(op + 4) = z;
    }
  }
}

extern "C" void kernel_launch(void* const* d_in, const int* in_sizes, int n_in,
                              void* d_out, int out_size, void* d_ws, size_t ws_size,
                              hipStream_t stream) {
  const float* hidden = (const float*)d_in[0];
  const float* alphas = (const float*)d_in[1];
  float* out = (float*)d_out;

  // ws layout: meta[Bn*MSTRIDE] u64 (16 KB, memset each call -- poison 0xAA
  // would read as published since bit30 of 0xAAAAAAAA is set).
  uint64_t* meta = (uint64_t*)d_ws;
  hipMemsetAsync(meta, 0, (size_t)Bn * MSTRIDE * sizeof(uint64_t), stream);

  const int nblocks = Bn + NTCH * Bn;   // 32 producers + 1600 consumers
  cif_fused_kernel<<<nblocks, 64, 0, stream>>>(hidden, alphas, meta, out);
}

// Round 23
// 56.110 us; speedup vs baseline: 1.3927x; 1.1583x over previous
//
#include <hip/hip_runtime.h>
#include <stdint.h>

static constexpr int   Bn      = 32;
static constexpr int   Tn      = 2000;
static constexpr int   Hn      = 512;
static constexpr int   Ln      = 256;     // max_label_len
static constexpr float kThresh = 0.95f;
static constexpr int   TCHUNK  = 40;      // meta granularity (consumer chunk)
static constexpr int   NTCH    = Tn / TCHUNK;   // 50
static constexpr int   CSPLIT  = 2;       // consumer blocks per (tc, b)
static constexpr int   MSTRIDE = 64;            // meta entries per row (padded)
static constexpr unsigned PUBF = 0x40000000u;   // published flag (low word)

// ---------------------------------------------------------------------------
// Fused producer-consumer CIF. R23 = R22's spill-proof producer + consumer
// latency fixes. R22 counters: occupancy 13.5% (1 wave/SIMD), consumer BW
// 1.05 TB/s -- each replay step loads h[t] then immediately consumes it ->
// vmcnt(0) per step -> full memory latency exposed, no TLP to hide it.
// Fix 1 (TLP): CSPLIT=2 -- two consumer blocks per (tc,b), each owning half
// of H (lane x float4), 3200 consumer waves (still all co-resident: 8.5 KB
// LDS/block -> 18 blocks/CU). Fix 2 (ILP): depth-2 prefetch -- h[t+1] load
// issues before h[t] is consumed (ping-pong named float4, clamped in-chunk).
//
// Producer (blocks 0..31): R22 verbatim -- LDS-staged row, depth-5 rotation
// of named float4 (no vmem, no arrays in the chain), meta published every
// 40 steps as ONE relaxed 8-B atomic (meta IS the flag).
// Consumers: exclusive ownership of segments CLOSING in chunk tc, walk-back
// re-derives the straddler opening, ascending-t accumulation (absmax 0.0 in
// R18-R22), tc=NTCH-1 zero-fills [fc,256). No atomics, no pre-zero pass.
// ---------------------------------------------------------------------------
__global__ __launch_bounds__(64, 1) void cif_fused_kernel(
    const float* __restrict__ hidden,
    const float* __restrict__ alphas,
    uint64_t* __restrict__ meta,     // [Bn*MSTRIDE]
    float* __restrict__ out) {
  const int lane = threadIdx.x;
  __shared__ __align__(16) float alds[Tn + 64];   // +pad: tail prefetch safe

  if (blockIdx.x < Bn) {
    // ---------------- producer: serial scan for row b ----------------
    __builtin_amdgcn_s_setprio(3);
    const int b = blockIdx.x;
    {  // stage row -> LDS, coalesced (one-time cost, outside the chain)
      const float4* __restrict__ arow =
          reinterpret_cast<const float4*>(alphas + (size_t)b * Tn);
      for (int i = lane; i < Tn / 4; i += 64)
        *reinterpret_cast<float4*>(&alds[4 * i]) = arow[i];
      for (int i = Tn / 4 + lane; i < (Tn + 64) / 4; i += 64)
        *reinterpret_cast<float4*>(&alds[4 * i]) =
            make_float4(0.f, 0.f, 0.f, 0.f);
    }
    __syncthreads();

    const float4* __restrict__ lds4 =
        reinterpret_cast<const float4*>(&alds[0]);
    float I  = 0.0f;
    int   fc = 0;

    float4 q0 = lds4[0], q1 = lds4[1], q2 = lds4[2], q3 = lds4[3],
           q4 = lds4[4];
    int rd = 5;

    auto step4 = [&](const float4& q) {
#pragma unroll
      for (int j = 0; j < 4; ++j) {
        const float a = (j == 0) ? q.x : (j == 1) ? q.y : (j == 2) ? q.z : q.w;
        const float integ = I + a;            // reference op order
        const bool  fire  = integ > kThresh;
        I  = fire ? (integ - 1.0f) : integ;
        fc += fire ? 1 : 0;
      }
    };

    for (int c = 0; c < 100; ++c) {           // 20 steps per iteration
      if (lane == 0 && (c & 1) == 0) {        // state at t = 20c -> chunk c/2
        const uint64_t v = ((uint64_t)__float_as_uint(I) << 32) |
                           (uint64_t)(PUBF | (unsigned)fc);
        __hip_atomic_store(&meta[(size_t)b * MSTRIDE + (c >> 1)], v,
                           __ATOMIC_RELAXED, __HIP_MEMORY_SCOPE_AGENT);
      }
      step4(q0); q0 = lds4[rd + 0];           // reload right after consume
      step4(q1); q1 = lds4[rd + 1];
      step4(q2); q2 = lds4[rd + 2];
      step4(q3); q3 = lds4[rd + 3];
      step4(q4); q4 = lds4[rd + 4];
      rd += 5;
    }
    return;
  }

  // ---------------- consumer: (chunk tc, row b, half) ----------------
  const int idx  = blockIdx.x - Bn;
  const int b    = idx & (Bn - 1);
  const int q    = idx >> 5;                // 0..NTCH*CSPLIT-1, low q first
  const int tc   = q >> 1;                  // low blockIdx -> low tc
  const int half = q & 1;
  const int t_start = tc * TCHUNK;
  const int col  = half * (Hn / CSPLIT) + lane * 4;   // float4 per lane

  auto wait_meta = [&](int c) -> uint64_t {
    const uint64_t* p = &meta[(size_t)b * MSTRIDE + c];
    uint64_t v;
    for (;;) {
      v = __hip_atomic_load(p, __ATOMIC_RELAXED, __HIP_MEMORY_SCOPE_AGENT);
      if ((unsigned)v & PUBF) break;
      __builtin_amdgcn_s_sleep(16);
    }
    return v;
  };

  const float* __restrict__ arow = alphas + (size_t)b * Tn;

  // Chunk-start state (bit-exact from producer).
  float I; int s;
  if (tc == 0) { I = 0.0f; s = 0; }
  else {
    const uint64_t v = wait_meta(tc);
    I = __uint_as_float((unsigned)(v >> 32));
    s = (int)((unsigned)v & 0xFFFFu);
  }

  // Walk back: find t_prev (last fire before t_start) and its remainder.
  int   t_prev   = -1;
  float rem_prev = 0.0f;
  for (int k = 1; tc - k >= 0 && t_prev < 0; ++k) {
    const int ck = tc - k;
    float Ik;
    if (ck == 0) Ik = 0.0f;
    else {
      const uint64_t v = wait_meta(ck);
      Ik = __uint_as_float((unsigned)(v >> 32));
    }
    const float* __restrict__ ap = arow + ck * TCHUNK;
    int lt = -1; float lrem = 0.0f;
#pragma unroll
    for (int j = 0; j < TCHUNK; ++j) {
      const float a     = ap[j];               // uniform scalar load
      const float integ = Ik + a;              // reference op order
      const bool  fire  = integ > kThresh;
      if (fire) { lt = ck * TCHUNK + j; lrem = a - (1.0f - Ik); }
      Ik = fire ? (integ - 1.0f) : integ;
    }
    if (lt >= 0) { t_prev = lt; rem_prev = lrem; }
  }

  const float* __restrict__ hb = hidden + (size_t)b * Tn * Hn + col;
  float4 acc = make_float4(0.f, 0.f, 0.f, 0.f);

  auto loadh = [&](int t) -> float4 {
    return *reinterpret_cast<const float4*>(hb + (size_t)t * Hn);
  };

  if (t_prev >= 0) {            // opening: frame = rem * h[t_prev]
    const float4 h = loadh(t_prev);
    acc.x = rem_prev * h.x; acc.y = rem_prev * h.y;
    acc.z = rem_prev * h.z; acc.w = rem_prev * h.w;
  }
  for (int t = t_prev + 1; t < t_start; ++t) {   // straddler interior rows
    const float a  = arow[t];
    const float4 h = loadh(t);
    acc.x += a * h.x; acc.y += a * h.y;
    acc.z += a * h.z; acc.w += a * h.w;
  }

  // Replay chunk tc with depth-2 h prefetch; close/store owned segments.
  float4 hc = loadh(t_start);
  for (int j = 0; j < TCHUNK; ++j) {
    const int t  = t_start + j;
    const int tn = (j + 1 < TCHUNK) ? t + 1 : t;   // clamp in-chunk
    const float4 hn = loadh(tn);             // issue BEFORE consuming hc
    const float a     = arow[t];             // uniform scalar load
    const float integ = I + a;               // reference op order
    const bool  fire  = integ > kThresh;     // wave-uniform
    if (fire) {
      const float cw = 1.0f - I;             // dist_completion
      acc.x += cw * hc.x; acc.y += cw * hc.y;
      acc.z += cw * hc.z; acc.w += cw * hc.w;
      if (s < Ln) {
        float* op = out + ((size_t)b * Ln + s) * Hn + col;
        *reinterpret_cast<float4*>(op) = acc;
      }
      const float rem = a - cw;              // remainds -> opens next segment
      acc.x = rem * hc.x; acc.y = rem * hc.y;
      acc.z = rem * hc.z; acc.w = rem * hc.w;
      s += 1;
      I  = integ - 1.0f;
    } else {
      acc.x += a * hc.x; acc.y += a * hc.y;
      acc.z += a * hc.z; acc.w += a * hc.w;
      I = integ;
    }
    hc = hn;
  }
  // Open tail is owned by consumer (tc+1); nothing more to store...
  if (tc == NTCH - 1) {                      // ...except zero-fill at the end
    const float4 z = make_float4(0.f, 0.f, 0.f, 0.f);
    for (int s2 = s; s2 < Ln; ++s2) {
      float* op = out + ((size_t)b * Ln + s2) * Hn + col;
      *reinterpret_cast<float4*>(op) = z;
    }
  }
}

extern "C" void kernel_launch(void* const* d_in, const int* in_sizes, int n_in,
                              void* d_out, int out_size, void* d_ws, size_t ws_size,
                              hipStream_t stream) {
  const float* hidden = (const float*)d_in[0];
  const float* alphas = (const float*)d_in[1];
  float* out = (float*)d_out;

  // ws layout: meta[Bn*MSTRIDE] u64 (16 KB, memset each call -- poison 0xAA
  // would read as published since bit30 of 0xAAAAAAAA is set).
  uint64_t* meta = (uint64_t*)d_ws;
  hipMemsetAsync(meta, 0, (size_t)Bn * MSTRIDE * sizeof(uint64_t), stream);

  const int nblocks = Bn + NTCH * Bn * CSPLIT;  // 32 producers + 3200 consumers
  cif_fused_kernel<<<nblocks, 64, 0, stream>>>(hidden, alphas, meta, out);
}